// Round 1
// 904.583 us; speedup vs baseline: 1.0208x; 1.0208x over previous
//
#include <hip/hip_runtime.h>

typedef unsigned short u16;
typedef float f32x4 __attribute__((ext_vector_type(4)));
typedef __bf16 bf16x8 __attribute__((ext_vector_type(8)));

#define AS1 __attribute__((address_space(1)))
#define AS3 __attribute__((address_space(3)))

__device__ __forceinline__ float bf2f(u16 h) {
  return __uint_as_float(((unsigned)h) << 16);
}
__device__ __forceinline__ u16 f2bf(float f) {
  unsigned u = __float_as_uint(f);
  unsigned r = (u + 0x7FFFu + ((u >> 16) & 1u)) >> 16;
  return (u16)r;
}
__device__ __forceinline__ void gload16(const u16* g, u16* l) {
  __builtin_amdgcn_global_load_lds((const AS1 void*)g, (AS3 void*)l, 16, 0, 0);
}

// ---------------------------------------------------------------- transpose
// out[C,R] = bf16(in[R,C]^T), in fp32; R,C multiples of 32
__global__ void transpose_k(const float* __restrict__ in, u16* __restrict__ out,
                            int R, int C) {
  __shared__ u16 t[32][33];
  int c0 = blockIdx.x * 32, r0 = blockIdx.y * 32;
  int tx = threadIdx.x & 31, ty = threadIdx.x >> 5; // 32 x 8
  for (int i = 0; i < 32; i += 8)
    t[ty + i][tx] = f2bf(in[(size_t)(r0 + ty + i) * C + c0 + tx]);
  __syncthreads();
  for (int i = 0; i < 32; i += 8)
    out[(size_t)(c0 + ty + i) * R + r0 + tx] = t[tx][ty + i];
}

// V(bf16) [16,1024, h*96+d] -> VT [bh][96][1024]
__global__ void vtrans_k(const u16* __restrict__ v, u16* __restrict__ vt) {
  __shared__ u16 t[32][33];
  int bh = blockIdx.z, b = bh >> 3, h = bh & 7;
  int n0 = blockIdx.y * 32, d0 = blockIdx.x * 32;
  int tx = threadIdx.x & 31, ty = threadIdx.x >> 5;
  const u16* src = v + (size_t)(b * 1024) * 768 + h * 96;
  for (int i = 0; i < 32; i += 8)
    t[ty + i][tx] = src[(size_t)(n0 + ty + i) * 768 + d0 + tx];
  __syncthreads();
  u16* dst = vt + ((size_t)bh * 96 + d0) * 1024 + n0;
  for (int i = 0; i < 32; i += 8)
    dst[(size_t)(ty + i) * 1024 + tx] = t[tx][ty + i];
}

// ---------------------------------------------------------------- layernorm
// fp32 x -> bf16 out; gamma/beta fp32
__global__ __launch_bounds__(256) void ln_f32_k(const float* __restrict__ x,
                                                const float* __restrict__ gamma,
                                                const float* __restrict__ beta,
                                                u16* __restrict__ out) {
  __shared__ float red[8];
  int row = blockIdx.x, t = threadIdx.x;
  const float* xr = x + (size_t)row * 768;
  float v[3], s = 0.f, s2 = 0.f;
#pragma unroll
  for (int i = 0; i < 3; i++) {
    v[i] = xr[t + i * 256];
    s += v[i]; s2 += v[i] * v[i];
  }
#pragma unroll
  for (int off = 1; off < 64; off <<= 1) {
    s += __shfl_xor(s, off, 64);
    s2 += __shfl_xor(s2, off, 64);
  }
  int w = t >> 6;
  if ((t & 63) == 0) { red[w] = s; red[4 + w] = s2; }
  __syncthreads();
  s = red[0] + red[1] + red[2] + red[3];
  s2 = red[4] + red[5] + red[6] + red[7];
  float mu = s * (1.f / 768.f);
  float var = s2 * (1.f / 768.f) - mu * mu;
  float rs = rsqrtf(var + 1e-5f);
  u16* orow = out + (size_t)row * 768;
#pragma unroll
  for (int i = 0; i < 3; i++) {
    int c = t + i * 256;
    orow[c] = f2bf((v[i] - mu) * rs * gamma[c] + beta[c]);
  }
}

// ---------------------------------------------------------------- GEMM
// EPI 0: C=bf16(A@Bt^T + bias)
// EPI 2: C=bf16(gelu(A@Bt^T + bias))
// EPI 4: C=fp32(A@Bt^T + bias + res_fp32)   (res may alias C 1:1)
#define BM 128
#define BN 128
#define BK 32

template <int EPI>
__global__ __launch_bounds__(256, 2) void gemm_bt(
    const u16* __restrict__ A, const u16* __restrict__ Bt,
    const float* __restrict__ bias, const float* __restrict__ res,
    void* __restrict__ Cv, int M, int N, int K) {
  __shared__ u16 As[BM * BK];
  __shared__ u16 Bs[BN * BK];
  int tid = threadIdx.x, lane = tid & 63, w = tid >> 6;
  int l15 = lane & 15, quad = lane >> 4;
  int wm = (w >> 1) * 64, wn = (w & 1) * 64;
  int m0 = blockIdx.x * BM, n0 = blockIdx.y * BN;
  f32x4 acc[4][4] = {};
  for (int k0 = 0; k0 < K; k0 += BK) {
    __syncthreads();
#pragma unroll
    for (int i = 0; i < 2; i++) {
      int c = w * 2 + i;
      int e = c * 512 + lane * 8;   // element offset in [128][32] tile
      int r = e >> 5, col = e & 31;
      gload16(A + (size_t)(m0 + r) * K + k0 + col, As + c * 512);
      gload16(Bt + (size_t)(n0 + r) * K + k0 + col, Bs + c * 512);
    }
    __syncthreads();
    bf16x8 af[4], bfv[4];
#pragma unroll
    for (int i = 0; i < 4; i++) {
      af[i] = *(const bf16x8*)(As + (wm + i * 16 + l15) * BK + quad * 8);
      bfv[i] = *(const bf16x8*)(Bs + (wn + i * 16 + l15) * BK + quad * 8);
    }
#pragma unroll
    for (int mt = 0; mt < 4; mt++)
#pragma unroll
      for (int nt = 0; nt < 4; nt++)
        acc[mt][nt] = __builtin_amdgcn_mfma_f32_16x16x32_bf16(
            af[mt], bfv[nt], acc[mt][nt], 0, 0, 0);
  }
  // epilogue: C/D layout col=lane&15, row=quad*4+reg (m89/m91-verified)
#pragma unroll
  for (int nt = 0; nt < 4; nt++) {
    int col = n0 + wn + nt * 16 + l15;
    float bv = bias[col];
#pragma unroll
    for (int mt = 0; mt < 4; mt++) {
      int row = m0 + wm + mt * 16 + quad * 4;
#pragma unroll
      for (int r = 0; r < 4; r++) {
        float v = acc[mt][nt][r] + bv;
        size_t idx = (size_t)(row + r) * N + col;
        if (EPI == 4) {
          v += res[idx];
          ((float*)Cv)[idx] = v;
        } else {
          if (EPI == 2) v = 0.5f * v * (1.0f + erff(v * 0.70710678118654752f));
          ((u16*)Cv)[idx] = f2bf(v);
        }
      }
    }
  }
}

// ---------------------------------------------------------------- attention
// flash-style; q,k: [16384,768] bf16 head-sliced; vt: [bh][96][1024]; o same
// LDS row strides padded +8 u16 (+16B) to kill bank conflicts:
//   qs/ks: 104 u16 = 208B = 20 banks mod 32 -> 16 rows hit 8 distinct
//          4-bank groups (2-way = free) instead of 2 groups (8-way).
//   vts/ps: 72 u16 = 144B = 4 banks mod 32 -> 2-way instead of 16-way.
#define QSS 104
#define VSS 72
#define PSS 72
__global__ __launch_bounds__(256, 2) void attn_k(const u16* __restrict__ q,
                                                 const u16* __restrict__ k,
                                                 const u16* __restrict__ vt,
                                                 u16* __restrict__ o) {
  __shared__ u16 qs[64 * QSS];
  __shared__ u16 ks[64 * QSS];
  __shared__ u16 vts[96 * VSS];
  __shared__ u16 ps[4 * 16 * PSS];
  int tid = threadIdx.x, lane = tid & 63, w = tid >> 6;
  int l15 = lane & 15, quad = lane >> 4;
  int qt = blockIdx.x, bh = blockIdx.y;
  int b = bh >> 3, h = bh & 7;
  const u16* qbase = q + (size_t)(b * 1024 + qt * 64) * 768 + h * 96;
  const u16* kbase = k + (size_t)(b * 1024) * 768 + h * 96;
  const u16* vtbase = vt + (size_t)bh * 96 * 1024;
  for (int c = tid; c < 768; c += 256) {
    int r = c / 12, off = (c % 12) * 8;
    *(uint4*)(qs + r * QSS + off) = *(const uint4*)(qbase + (size_t)r * 768 + off);
  }
  float mi[4], li[4];
#pragma unroll
  for (int r = 0; r < 4; r++) { mi[r] = -1e30f; li[r] = 0.f; }
  f32x4 oacc[6] = {};
  const float scale = 0.10206207261596577f; // 1/sqrt(96)
  for (int kt = 0; kt < 16; kt++) {
    __syncthreads();
    for (int c = tid; c < 768; c += 256) {
      int r = c / 12, off = (c % 12) * 8;
      *(uint4*)(ks + r * QSS + off) =
          *(const uint4*)(kbase + (size_t)(kt * 64 + r) * 768 + off);
    }
    for (int c = tid; c < 768; c += 256) {
      int r = c >> 3, off = (c & 7) * 8;
      *(uint4*)(vts + r * VSS + off) =
          *(const uint4*)(vtbase + (size_t)r * 1024 + kt * 64 + off);
    }
    __syncthreads();
    f32x4 s[4] = {};
#pragma unroll
    for (int kk = 0; kk < 3; kk++) {
      bf16x8 a = *(const bf16x8*)(qs + (w * 16 + l15) * QSS + kk * 32 + quad * 8);
#pragma unroll
      for (int nt = 0; nt < 4; nt++) {
        bf16x8 bb = *(const bf16x8*)(ks + (nt * 16 + l15) * QSS + kk * 32 + quad * 8);
        s[nt] = __builtin_amdgcn_mfma_f32_16x16x32_bf16(a, bb, s[nt], 0, 0, 0);
      }
    }
#pragma unroll
    for (int r = 0; r < 4; r++) {
      float sv[4], mx = -1e30f;
#pragma unroll
      for (int nt = 0; nt < 4; nt++) {
        sv[nt] = s[nt][r] * scale;
        mx = fmaxf(mx, sv[nt]);
      }
#pragma unroll
      for (int off = 1; off < 16; off <<= 1) mx = fmaxf(mx, __shfl_xor(mx, off, 16));
      float mnew = fmaxf(mi[r], mx);
      float alpha = __expf(mi[r] - mnew);
      float rs = 0.f;
#pragma unroll
      for (int nt = 0; nt < 4; nt++) { sv[nt] = __expf(sv[nt] - mnew); rs += sv[nt]; }
#pragma unroll
      for (int off = 1; off < 16; off <<= 1) rs += __shfl_xor(rs, off, 16);
      li[r] = li[r] * alpha + rs;
      mi[r] = mnew;
#pragma unroll
      for (int ht = 0; ht < 6; ht++) oacc[ht][r] *= alpha;
      int prow = quad * 4 + r;
#pragma unroll
      for (int nt = 0; nt < 4; nt++)
        ps[w * 16 * PSS + prow * PSS + nt * 16 + l15] = f2bf(sv[nt]);
    }
    __syncthreads();
#pragma unroll
    for (int kk = 0; kk < 2; kk++) {
      bf16x8 a = *(const bf16x8*)(ps + w * 16 * PSS + l15 * PSS + kk * 32 + quad * 8);
#pragma unroll
      for (int ht = 0; ht < 6; ht++) {
        bf16x8 bb = *(const bf16x8*)(vts + (ht * 16 + l15) * VSS + kk * 32 + quad * 8);
        oacc[ht] = __builtin_amdgcn_mfma_f32_16x16x32_bf16(a, bb, oacc[ht], 0, 0, 0);
      }
    }
  }
  u16* obase = o + (size_t)(b * 1024 + qt * 64 + w * 16) * 768 + h * 96;
#pragma unroll
  for (int r = 0; r < 4; r++) {
    float inv = 1.0f / li[r];
    int row = quad * 4 + r;
#pragma unroll
    for (int ht = 0; ht < 6; ht++)
      obase[(size_t)row * 768 + ht * 16 + l15] = f2bf(oacc[ht][r] * inv);
  }
}

// ---------------------------------------------------------------- launch
// d_out is FP32 (reference output dtype). y1 lives in d_out as fp32;
// final GEMM reads res=y1 and writes out 1:1-aliased (safe: each (row,col)
// is read-then-written by exactly one thread).
// ws: weights 14.2MB + 4 x 25.2MB bf16 buffers = 115MB (R2-proven safe).
extern "C" void kernel_launch(void* const* d_in, const int* in_sizes, int n_in,
                              void* d_out, int out_size, void* d_ws,
                              size_t ws_size, hipStream_t stream) {
  const float* x = (const float*)d_in[0];
  const float* gamma = (const float*)d_in[1];
  const float* beta = (const float*)d_in[2];
  const float* Wq = (const float*)d_in[3];
  const float* bq = (const float*)d_in[4];
  const float* Wk = (const float*)d_in[5];
  const float* bk = (const float*)d_in[6];
  const float* Wv = (const float*)d_in[7];
  const float* bv = (const float*)d_in[8];
  const float* Wo = (const float*)d_in[9];
  const float* bo = (const float*)d_in[10];
  const float* W1 = (const float*)d_in[11];
  const float* b1 = (const float*)d_in[12];
  const float* W2 = (const float*)d_in[13];
  const float* b2 = (const float*)d_in[14];
  float* out = (float*)d_out;

  char* ws = (char*)d_ws;
  size_t off = 0;
  auto alloc = [&](size_t elems) {
    u16* p = (u16*)(ws + off);
    off += elems * sizeof(u16);
    return p;
  };
  u16* WqT = alloc(768 * 768);
  u16* WkT = alloc(768 * 768);
  u16* WvT = alloc(768 * 768);
  u16* WoT = alloc(768 * 768);
  u16* W1T = alloc((size_t)768 * 3072);    // [3072,768]
  u16* W2T = alloc((size_t)3072 * 768);    // [768,3072]
  u16* hb = alloc((size_t)16384 * 768);    // h -> VT
  u16* qb = alloc((size_t)16384 * 768);    // q
  u16* kb = alloc((size_t)16384 * 768);    // k -> h2
  u16* vb = alloc((size_t)16384 * 768);    // v -> attn_out -> f-chunk

  // weight transposes fp32 -> bf16 [N,K]
  transpose_k<<<dim3(24, 24), 256, 0, stream>>>(Wq, WqT, 768, 768);
  transpose_k<<<dim3(24, 24), 256, 0, stream>>>(Wk, WkT, 768, 768);
  transpose_k<<<dim3(24, 24), 256, 0, stream>>>(Wv, WvT, 768, 768);
  transpose_k<<<dim3(24, 24), 256, 0, stream>>>(Wo, WoT, 768, 768);
  transpose_k<<<dim3(96, 24), 256, 0, stream>>>(W1, W1T, 768, 3072);
  transpose_k<<<dim3(24, 96), 256, 0, stream>>>(W2, W2T, 3072, 768);

  // LN1: x(fp32) -> h(bf16)
  ln_f32_k<<<16384, 256, 0, stream>>>(x, gamma, beta, hb);
  // QKV projections (bf16)
  gemm_bt<0><<<dim3(128, 6), 256, 0, stream>>>(hb, WqT, bq, nullptr, qb,
                                               16384, 768, 768);
  gemm_bt<0><<<dim3(128, 6), 256, 0, stream>>>(hb, WkT, bk, nullptr, kb,
                                               16384, 768, 768);
  gemm_bt<0><<<dim3(128, 6), 256, 0, stream>>>(hb, WvT, bv, nullptr, vb,
                                               16384, 768, 768);
  // V -> VT [bh][96][1024] into hb (h dead)
  vtrans_k<<<dim3(3, 32, 128), 256, 0, stream>>>(vb, hb);
  // attention -> vb (v dead after vtrans)
  attn_k<<<dim3(16, 128), 256, 0, stream>>>(qb, kb, hb, vb);
  // y1(fp32, in d_out) = attn @ Wo + bo + x
  gemm_bt<4><<<dim3(128, 6), 256, 0, stream>>>(vb, WoT, bo, x, out,
                                               16384, 768, 768);
  // h2 = LN(y1) -> kb (k dead)
  ln_f32_k<<<16384, 256, 0, stream>>>(out, gamma, beta, kb);
  // FFN in 4 M-chunks of 4096 rows; f-chunk [4096,3072] bf16 fits vb
  for (int c = 0; c < 4; c++) {
    const u16* h2c = kb + (size_t)c * 4096 * 768;
    const float* y1c = out + (size_t)c * 4096 * 768;
    float* outc = out + (size_t)c * 4096 * 768;
    gemm_bt<2><<<dim3(32, 24), 256, 0, stream>>>(h2c, W1T, b1, nullptr, vb,
                                                 4096, 3072, 768);
    gemm_bt<4><<<dim3(32, 6), 256, 0, stream>>>(vb, W2T, b2, y1c, outc,
                                                4096, 768, 3072);
  }
}

// Round 3
// 858.206 us; speedup vs baseline: 1.0760x; 1.0540x over previous
//
#include <hip/hip_runtime.h>

typedef unsigned short u16;
typedef float f32x4 __attribute__((ext_vector_type(4)));
typedef __bf16 bf16x8 __attribute__((ext_vector_type(8)));

#define AS1 __attribute__((address_space(1)))
#define AS3 __attribute__((address_space(3)))

__device__ __forceinline__ float bf2f(u16 h) {
  return __uint_as_float(((unsigned)h) << 16);
}
__device__ __forceinline__ u16 f2bf(float f) {
  unsigned u = __float_as_uint(f);
  unsigned r = (u + 0x7FFFu + ((u >> 16) & 1u)) >> 16;
  return (u16)r;
}
__device__ __forceinline__ void gload16(const u16* g, u16* l) {
  __builtin_amdgcn_global_load_lds((const AS1 void*)g, (AS3 void*)l, 16, 0, 0);
}

// ---------------------------------------------------------------- transpose
// out[C,R] = bf16(in[R,C]^T), in fp32; R,C multiples of 32
__global__ void transpose_k(const float* __restrict__ in, u16* __restrict__ out,
                            int R, int C) {
  __shared__ u16 t[32][33];
  int c0 = blockIdx.x * 32, r0 = blockIdx.y * 32;
  int tx = threadIdx.x & 31, ty = threadIdx.x >> 5; // 32 x 8
  for (int i = 0; i < 32; i += 8)
    t[ty + i][tx] = f2bf(in[(size_t)(r0 + ty + i) * C + c0 + tx]);
  __syncthreads();
  for (int i = 0; i < 32; i += 8)
    out[(size_t)(c0 + ty + i) * R + r0 + tx] = t[tx][ty + i];
}

// V(bf16) [16,1024, h*96+d] -> VT [bh][96][1024]
__global__ void vtrans_k(const u16* __restrict__ v, u16* __restrict__ vt) {
  __shared__ u16 t[32][33];
  int bh = blockIdx.z, b = bh >> 3, h = bh & 7;
  int n0 = blockIdx.y * 32, d0 = blockIdx.x * 32;
  int tx = threadIdx.x & 31, ty = threadIdx.x >> 5;
  const u16* src = v + (size_t)(b * 1024) * 768 + h * 96;
  for (int i = 0; i < 32; i += 8)
    t[ty + i][tx] = src[(size_t)(n0 + ty + i) * 768 + d0 + tx];
  __syncthreads();
  u16* dst = vt + ((size_t)bh * 96 + d0) * 1024 + n0;
  for (int i = 0; i < 32; i += 8)
    dst[(size_t)(ty + i) * 1024 + tx] = t[tx][ty + i];
}

// ---------------------------------------------------------------- layernorm
// fp32 x -> bf16 out; gamma/beta fp32
__global__ __launch_bounds__(256) void ln_f32_k(const float* __restrict__ x,
                                                const float* __restrict__ gamma,
                                                const float* __restrict__ beta,
                                                u16* __restrict__ out) {
  __shared__ float red[8];
  int row = blockIdx.x, t = threadIdx.x;
  const float* xr = x + (size_t)row * 768;
  float v[3], s = 0.f, s2 = 0.f;
#pragma unroll
  for (int i = 0; i < 3; i++) {
    v[i] = xr[t + i * 256];
    s += v[i]; s2 += v[i] * v[i];
  }
#pragma unroll
  for (int off = 1; off < 64; off <<= 1) {
    s += __shfl_xor(s, off, 64);
    s2 += __shfl_xor(s2, off, 64);
  }
  int w = t >> 6;
  if ((t & 63) == 0) { red[w] = s; red[4 + w] = s2; }
  __syncthreads();
  s = red[0] + red[1] + red[2] + red[3];
  s2 = red[4] + red[5] + red[6] + red[7];
  float mu = s * (1.f / 768.f);
  float var = s2 * (1.f / 768.f) - mu * mu;
  float rs = rsqrtf(var + 1e-5f);
  u16* orow = out + (size_t)row * 768;
#pragma unroll
  for (int i = 0; i < 3; i++) {
    int c = t + i * 256;
    orow[c] = f2bf((v[i] - mu) * rs * gamma[c] + beta[c]);
  }
}

// ---------------------------------------------------------------- GEMM
// EPI 0: C=bf16(A@Bt^T + bias)
// EPI 2: C=bf16(gelu(A@Bt^T + bias))
// EPI 4: C=fp32(A@Bt^T + bias + res_fp32)   (res may alias C 1:1)
#define BM 128
#define BN 128
#define BK 32

template <int EPI>
__global__ __launch_bounds__(256, 2) void gemm_bt(
    const u16* __restrict__ A, const u16* __restrict__ Bt,
    const float* __restrict__ bias, const float* __restrict__ res,
    void* __restrict__ Cv, int M, int N, int K) {
  __shared__ u16 As[BM * BK];
  __shared__ u16 Bs[BN * BK];
  int tid = threadIdx.x, lane = tid & 63, w = tid >> 6;
  int l15 = lane & 15, quad = lane >> 4;
  int wm = (w >> 1) * 64, wn = (w & 1) * 64;
  int m0 = blockIdx.x * BM, n0 = blockIdx.y * BN;
  f32x4 acc[4][4] = {};
  for (int k0 = 0; k0 < K; k0 += BK) {
    __syncthreads();
#pragma unroll
    for (int i = 0; i < 2; i++) {
      int c = w * 2 + i;
      int e = c * 512 + lane * 8;   // element offset in [128][32] tile
      int r = e >> 5, col = e & 31;
      gload16(A + (size_t)(m0 + r) * K + k0 + col, As + c * 512);
      gload16(Bt + (size_t)(n0 + r) * K + k0 + col, Bs + c * 512);
    }
    __syncthreads();
    bf16x8 af[4], bfv[4];
#pragma unroll
    for (int i = 0; i < 4; i++) {
      af[i] = *(const bf16x8*)(As + (wm + i * 16 + l15) * BK + quad * 8);
      bfv[i] = *(const bf16x8*)(Bs + (wn + i * 16 + l15) * BK + quad * 8);
    }
#pragma unroll
    for (int mt = 0; mt < 4; mt++)
#pragma unroll
      for (int nt = 0; nt < 4; nt++)
        acc[mt][nt] = __builtin_amdgcn_mfma_f32_16x16x32_bf16(
            af[mt], bfv[nt], acc[mt][nt], 0, 0, 0);
  }
  // epilogue: C/D layout col=lane&15, row=quad*4+reg (m89/m91-verified)
#pragma unroll
  for (int nt = 0; nt < 4; nt++) {
    int col = n0 + wn + nt * 16 + l15;
    float bv = bias[col];
#pragma unroll
    for (int mt = 0; mt < 4; mt++) {
      int row = m0 + wm + mt * 16 + quad * 4;
#pragma unroll
      for (int r = 0; r < 4; r++) {
        float v = acc[mt][nt][r] + bv;
        size_t idx = (size_t)(row + r) * N + col;
        if (EPI == 4) {
          v += res[idx];
          ((float*)Cv)[idx] = v;
        } else {
          if (EPI == 2) v = 0.5f * v * (1.0f + erff(v * 0.70710678118654752f));
          ((u16*)Cv)[idx] = f2bf(v);
        }
      }
    }
  }
}

// ---------------------------------------------------------------- attention
// flash-style; q,k: [16384,768] bf16 head-sliced; vt: [bh][96][1024]; o same
// LDS row strides padded +8 u16 (+16B): qs/ks 104, vts/ps 72 (R1: conflicts
// 3.4e7 -> 1.6e7, fragment reads now 2-way=free).
// R2: 2-phase schedule — double-buffered ks/vts, unconditional wraparound
// prefetch of tile (kt+1)&15 into regs before compute of kt (T14
// async-stage split), ds_write after PV, ONE barrier per kt (was 3).
// ps is wave-private: lgkmcnt(0) fence instead of a barrier. No asm pin:
// any asm use of the loaded regs would force vmcnt(0) at the issue site.
#define QSS 104
#define VSS 72
#define PSS 72
__global__ __launch_bounds__(256, 2) void attn_k(const u16* __restrict__ q,
                                                 const u16* __restrict__ k,
                                                 const u16* __restrict__ vt,
                                                 u16* __restrict__ o) {
  __shared__ u16 qs[64 * QSS];
  __shared__ u16 ks[2][64 * QSS];
  __shared__ u16 vts[2][96 * VSS];
  __shared__ u16 ps[4 * 16 * PSS];
  int tid = threadIdx.x, lane = tid & 63, w = tid >> 6;
  int l15 = lane & 15, quad = lane >> 4;
  int qt = blockIdx.x, bh = blockIdx.y;
  int b = bh >> 3, h = bh & 7;
  const u16* qbase = q + (size_t)(b * 1024 + qt * 64) * 768 + h * 96;
  const u16* kbase = k + (size_t)(b * 1024) * 768 + h * 96;
  const u16* vtbase = vt + (size_t)bh * 96 * 1024;
  // per-thread staging coordinates (3 chunks each for K and VT)
  int kr[3], ko[3], vr[3], vo[3];
#pragma unroll
  for (int i = 0; i < 3; i++) {
    int c = tid + i * 256;
    kr[i] = c / 12; ko[i] = (c % 12) * 8;
    vr[i] = c >> 3; vo[i] = (c & 7) * 8;
  }
  // Q stage
#pragma unroll
  for (int i = 0; i < 3; i++)
    *(uint4*)(qs + kr[i] * QSS + ko[i]) =
        *(const uint4*)(qbase + (size_t)kr[i] * 768 + ko[i]);
  // prologue: stage tile 0
  uint4 kreg[3], vreg[3];
#pragma unroll
  for (int i = 0; i < 3; i++) {
    kreg[i] = *(const uint4*)(kbase + (size_t)kr[i] * 768 + ko[i]);
    vreg[i] = *(const uint4*)(vtbase + (size_t)vr[i] * 1024 + vo[i]);
  }
#pragma unroll
  for (int i = 0; i < 3; i++) {
    *(uint4*)(ks[0] + kr[i] * QSS + ko[i]) = kreg[i];
    *(uint4*)(vts[0] + vr[i] * VSS + vo[i]) = vreg[i];
  }
  __syncthreads();

  float mi[4], li[4];
#pragma unroll
  for (int r = 0; r < 4; r++) { mi[r] = -1e30f; li[r] = 0.f; }
  f32x4 oacc[6] = {};
  const float scale = 0.10206207261596577f; // 1/sqrt(96)
  for (int kt = 0; kt < 16; kt++) {
    int cur = kt & 1, nxt = cur ^ 1;
    int ktn = (kt + 1) & 15;  // wraparound: last iter re-fetches tile 0
    // issue prefetch of next tile (completion waited only at the ds_write
    // block after PV — ~2000cy of compute hides the latency)
#pragma unroll
    for (int i = 0; i < 3; i++) {
      kreg[i] = *(const uint4*)(kbase + (size_t)(ktn * 64 + kr[i]) * 768 + ko[i]);
      vreg[i] = *(const uint4*)(vtbase + (size_t)vr[i] * 1024 + ktn * 64 + vo[i]);
    }
    // QK^T on current buffer
    f32x4 s[4] = {};
#pragma unroll
    for (int kk = 0; kk < 3; kk++) {
      bf16x8 a = *(const bf16x8*)(qs + (w * 16 + l15) * QSS + kk * 32 + quad * 8);
#pragma unroll
      for (int nt = 0; nt < 4; nt++) {
        bf16x8 bb =
            *(const bf16x8*)(ks[cur] + (nt * 16 + l15) * QSS + kk * 32 + quad * 8);
        s[nt] = __builtin_amdgcn_mfma_f32_16x16x32_bf16(a, bb, s[nt], 0, 0, 0);
      }
    }
    // online softmax (4 rows per lane-group via quad)
#pragma unroll
    for (int r = 0; r < 4; r++) {
      float sv[4], mx = -1e30f;
#pragma unroll
      for (int nt = 0; nt < 4; nt++) {
        sv[nt] = s[nt][r] * scale;
        mx = fmaxf(mx, sv[nt]);
      }
#pragma unroll
      for (int off = 1; off < 16; off <<= 1) mx = fmaxf(mx, __shfl_xor(mx, off, 16));
      float mnew = fmaxf(mi[r], mx);
      float alpha = __expf(mi[r] - mnew);
      float rs = 0.f;
#pragma unroll
      for (int nt = 0; nt < 4; nt++) { sv[nt] = __expf(sv[nt] - mnew); rs += sv[nt]; }
#pragma unroll
      for (int off = 1; off < 16; off <<= 1) rs += __shfl_xor(rs, off, 16);
      li[r] = li[r] * alpha + rs;
      mi[r] = mnew;
#pragma unroll
      for (int ht = 0; ht < 6; ht++) oacc[ht][r] *= alpha;
      int prow = quad * 4 + r;
#pragma unroll
      for (int nt = 0; nt < 4; nt++)
        ps[w * 16 * PSS + prow * PSS + nt * 16 + l15] = f2bf(sv[nt]);
    }
    // ps is wave-private: order write->read within the wave, no barrier
    asm volatile("s_waitcnt lgkmcnt(0)" ::: "memory");
    // PV on current buffer
#pragma unroll
    for (int kk = 0; kk < 2; kk++) {
      bf16x8 a = *(const bf16x8*)(ps + w * 16 * PSS + l15 * PSS + kk * 32 + quad * 8);
#pragma unroll
      for (int ht = 0; ht < 6; ht++) {
        bf16x8 bb =
            *(const bf16x8*)(vts[cur] + (ht * 16 + l15) * VSS + kk * 32 + quad * 8);
        oacc[ht] = __builtin_amdgcn_mfma_f32_16x16x32_bf16(a, bb, oacc[ht], 0, 0, 0);
      }
    }
    // write prefetched tile into next buffer (freed by the barrier that
    // ended iteration kt-1), then the single per-iteration barrier
#pragma unroll
    for (int i = 0; i < 3; i++) {
      *(uint4*)(ks[nxt] + kr[i] * QSS + ko[i]) = kreg[i];
      *(uint4*)(vts[nxt] + vr[i] * VSS + vo[i]) = vreg[i];
    }
    __syncthreads();
  }
  u16* obase = o + (size_t)(b * 1024 + qt * 64 + w * 16) * 768 + h * 96;
#pragma unroll
  for (int r = 0; r < 4; r++) {
    float inv = 1.0f / li[r];
    int row = quad * 4 + r;
#pragma unroll
    for (int ht = 0; ht < 6; ht++)
      obase[(size_t)row * 768 + ht * 16 + l15] = f2bf(oacc[ht][r] * inv);
  }
}

// ---------------------------------------------------------------- launch
// d_out is FP32 (reference output dtype). y1 lives in d_out as fp32;
// final GEMM reads res=y1 and writes out 1:1-aliased (safe: each (row,col)
// is read-then-written by exactly one thread).
// ws: weights 14.2MB + 4 x 25.2MB bf16 buffers = 115MB (R2-proven safe).
extern "C" void kernel_launch(void* const* d_in, const int* in_sizes, int n_in,
                              void* d_out, int out_size, void* d_ws,
                              size_t ws_size, hipStream_t stream) {
  const float* x = (const float*)d_in[0];
  const float* gamma = (const float*)d_in[1];
  const float* beta = (const float*)d_in[2];
  const float* Wq = (const float*)d_in[3];
  const float* bq = (const float*)d_in[4];
  const float* Wk = (const float*)d_in[5];
  const float* bk = (const float*)d_in[6];
  const float* Wv = (const float*)d_in[7];
  const float* bv = (const float*)d_in[8];
  const float* Wo = (const float*)d_in[9];
  const float* bo = (const float*)d_in[10];
  const float* W1 = (const float*)d_in[11];
  const float* b1 = (const float*)d_in[12];
  const float* W2 = (const float*)d_in[13];
  const float* b2 = (const float*)d_in[14];
  float* out = (float*)d_out;

  char* ws = (char*)d_ws;
  size_t off = 0;
  auto alloc = [&](size_t elems) {
    u16* p = (u16*)(ws + off);
    off += elems * sizeof(u16);
    return p;
  };
  u16* WqT = alloc(768 * 768);
  u16* WkT = alloc(768 * 768);
  u16* WvT = alloc(768 * 768);
  u16* WoT = alloc(768 * 768);
  u16* W1T = alloc((size_t)768 * 3072);    // [3072,768]
  u16* W2T = alloc((size_t)3072 * 768);    // [768,3072]
  u16* hb = alloc((size_t)16384 * 768);    // h -> VT
  u16* qb = alloc((size_t)16384 * 768);    // q
  u16* kb = alloc((size_t)16384 * 768);    // k -> h2
  u16* vb = alloc((size_t)16384 * 768);    // v -> attn_out -> f-chunk

  // weight transposes fp32 -> bf16 [N,K]
  transpose_k<<<dim3(24, 24), 256, 0, stream>>>(Wq, WqT, 768, 768);
  transpose_k<<<dim3(24, 24), 256, 0, stream>>>(Wk, WkT, 768, 768);
  transpose_k<<<dim3(24, 24), 256, 0, stream>>>(Wv, WvT, 768, 768);
  transpose_k<<<dim3(24, 24), 256, 0, stream>>>(Wo, WoT, 768, 768);
  transpose_k<<<dim3(96, 24), 256, 0, stream>>>(W1, W1T, 768, 3072);
  transpose_k<<<dim3(24, 96), 256, 0, stream>>>(W2, W2T, 3072, 768);

  // LN1: x(fp32) -> h(bf16)
  ln_f32_k<<<16384, 256, 0, stream>>>(x, gamma, beta, hb);
  // QKV projections (bf16)
  gemm_bt<0><<<dim3(128, 6), 256, 0, stream>>>(hb, WqT, bq, nullptr, qb,
                                               16384, 768, 768);
  gemm_bt<0><<<dim3(128, 6), 256, 0, stream>>>(hb, WkT, bk, nullptr, kb,
                                               16384, 768, 768);
  gemm_bt<0><<<dim3(128, 6), 256, 0, stream>>>(hb, WvT, bv, nullptr, vb,
                                               16384, 768, 768);
  // V -> VT [bh][96][1024] into hb (h dead)
  vtrans_k<<<dim3(3, 32, 128), 256, 0, stream>>>(vb, hb);
  // attention -> vb (v dead after vtrans)
  attn_k<<<dim3(16, 128), 256, 0, stream>>>(qb, kb, hb, vb);
  // y1(fp32, in d_out) = attn @ Wo + bo + x
  gemm_bt<4><<<dim3(128, 6), 256, 0, stream>>>(vb, WoT, bo, x, out,
                                               16384, 768, 768);
  // h2 = LN(y1) -> kb (k dead)
  ln_f32_k<<<16384, 256, 0, stream>>>(out, gamma, beta, kb);
  // FFN in 4 M-chunks of 4096 rows; f-chunk [4096,3072] bf16 fits vb
  for (int c = 0; c < 4; c++) {
    const u16* h2c = kb + (size_t)c * 4096 * 768;
    const float* y1c = out + (size_t)c * 4096 * 768;
    float* outc = out + (size_t)c * 4096 * 768;
    gemm_bt<2><<<dim3(32, 24), 256, 0, stream>>>(h2c, W1T, b1, nullptr, vb,
                                                 4096, 3072, 768);
    gemm_bt<4><<<dim3(32, 6), 256, 0, stream>>>(vb, W2T, b2, y1c, outc,
                                                4096, 768, 3072);
  }
}

// Round 4
// 820.678 us; speedup vs baseline: 1.1252x; 1.0457x over previous
//
#include <hip/hip_runtime.h>

typedef unsigned short u16;
typedef float f32x4 __attribute__((ext_vector_type(4)));
typedef __bf16 bf16x8 __attribute__((ext_vector_type(8)));

#define AS1 __attribute__((address_space(1)))
#define AS3 __attribute__((address_space(3)))

__device__ __forceinline__ float bf2f(u16 h) {
  return __uint_as_float(((unsigned)h) << 16);
}
__device__ __forceinline__ u16 f2bf(float f) {
  unsigned u = __float_as_uint(f);
  unsigned r = (u + 0x7FFFu + ((u >> 16) & 1u)) >> 16;
  return (u16)r;
}
__device__ __forceinline__ void gload16(const u16* g, u16* l) {
  __builtin_amdgcn_global_load_lds((const AS1 void*)g, (AS3 void*)l, 16, 0, 0);
}

// ---------------------------------------------------------------- transpose
// out[C,R] = bf16(in[R,C]^T), in fp32; R,C multiples of 32
__global__ void transpose_k(const float* __restrict__ in, u16* __restrict__ out,
                            int R, int C) {
  __shared__ u16 t[32][33];
  int c0 = blockIdx.x * 32, r0 = blockIdx.y * 32;
  int tx = threadIdx.x & 31, ty = threadIdx.x >> 5; // 32 x 8
  for (int i = 0; i < 32; i += 8)
    t[ty + i][tx] = f2bf(in[(size_t)(r0 + ty + i) * C + c0 + tx]);
  __syncthreads();
  for (int i = 0; i < 32; i += 8)
    out[(size_t)(c0 + ty + i) * R + r0 + tx] = t[tx][ty + i];
}

// V(bf16) [16,1024, h*96+d] -> VT [bh][96][1024]
__global__ void vtrans_k(const u16* __restrict__ v, u16* __restrict__ vt) {
  __shared__ u16 t[32][33];
  int bh = blockIdx.z, b = bh >> 3, h = bh & 7;
  int n0 = blockIdx.y * 32, d0 = blockIdx.x * 32;
  int tx = threadIdx.x & 31, ty = threadIdx.x >> 5;
  const u16* src = v + (size_t)(b * 1024) * 768 + h * 96;
  for (int i = 0; i < 32; i += 8)
    t[ty + i][tx] = src[(size_t)(n0 + ty + i) * 768 + d0 + tx];
  __syncthreads();
  u16* dst = vt + ((size_t)bh * 96 + d0) * 1024 + n0;
  for (int i = 0; i < 32; i += 8)
    dst[(size_t)(ty + i) * 1024 + tx] = t[tx][ty + i];
}

// ---------------------------------------------------------------- layernorm
// fp32 x -> bf16 out; gamma/beta fp32
__global__ __launch_bounds__(256) void ln_f32_k(const float* __restrict__ x,
                                                const float* __restrict__ gamma,
                                                const float* __restrict__ beta,
                                                u16* __restrict__ out) {
  __shared__ float red[8];
  int row = blockIdx.x, t = threadIdx.x;
  const float* xr = x + (size_t)row * 768;
  float v[3], s = 0.f, s2 = 0.f;
#pragma unroll
  for (int i = 0; i < 3; i++) {
    v[i] = xr[t + i * 256];
    s += v[i]; s2 += v[i] * v[i];
  }
#pragma unroll
  for (int off = 1; off < 64; off <<= 1) {
    s += __shfl_xor(s, off, 64);
    s2 += __shfl_xor(s2, off, 64);
  }
  int w = t >> 6;
  if ((t & 63) == 0) { red[w] = s; red[4 + w] = s2; }
  __syncthreads();
  s = red[0] + red[1] + red[2] + red[3];
  s2 = red[4] + red[5] + red[6] + red[7];
  float mu = s * (1.f / 768.f);
  float var = s2 * (1.f / 768.f) - mu * mu;
  float rs = rsqrtf(var + 1e-5f);
  u16* orow = out + (size_t)row * 768;
#pragma unroll
  for (int i = 0; i < 3; i++) {
    int c = t + i * 256;
    orow[c] = f2bf((v[i] - mu) * rs * gamma[c] + beta[c]);
  }
}

// ---------------------------------------------------------------- GEMM
// EPI 0: C=bf16(A@Bt^T + bias)
// EPI 2: C=bf16(gelu(A@Bt^T + bias))
// EPI 4: C=fp32(A@Bt^T + bias + res_fp32)   (res may alias C 1:1)
// R4: BK=64 (half the barrier pairs), XOR-swizzled LDS (pre-swizzled global
// source since global_load_lds writes linearly; read with matching XOR ->
// 2-way conflict-free), XCD-aware block swizzle (each XCD owns a contiguous
// m-band x all n-tiles -> A panel L2-resident). Requires gridDim.x % 8 == 0.
#define BM 128
#define BN 128
#define BK 64

template <int EPI>
__global__ __launch_bounds__(256, 2) void gemm_bt(
    const u16* __restrict__ A, const u16* __restrict__ Bt,
    const float* __restrict__ bias, const float* __restrict__ res,
    void* __restrict__ Cv, int M, int N, int K) {
  __shared__ u16 As[BM * BK];
  __shared__ u16 Bs[BN * BK];
  int tid = threadIdx.x, lane = tid & 63, w = tid >> 6;
  int l15 = lane & 15, quad = lane >> 4;
  int wm = (w >> 1) * 64, wn = (w & 1) * 64;
  // XCD-aware swizzle: f = HW linear block id (x fastest)
  int GX = gridDim.x;
  int f = blockIdx.y * GX + blockIdx.x;
  int mpx = GX >> 3;                     // m-tiles per XCD
  int xcd = f & 7, idx = f >> 3;
  int m0 = (xcd * mpx + (idx % mpx)) * BM;
  int n0 = (idx / mpx) * BN;
  // staging coords: lane l covers row (c*8 + l>>3), col-slot (l&7)^(l>>3)
  int srow = lane >> 3;
  int scol = ((lane & 7) ^ srow) * 8;
  f32x4 acc[4][4] = {};
  for (int k0 = 0; k0 < K; k0 += BK) {
    __syncthreads();
#pragma unroll
    for (int i = 0; i < 4; i++) {
      int c = w * 4 + i;              // chunk: 8 rows of 64
      int r = c * 8 + srow;
      gload16(A + (size_t)(m0 + r) * K + k0 + scol, As + c * 512);
      gload16(Bt + (size_t)(n0 + r) * K + k0 + scol, Bs + c * 512);
    }
    __syncthreads();
#pragma unroll
    for (int kk = 0; kk < 2; kk++) {
      bf16x8 af[4], bfv[4];
      int sa = ((kk * 4 + quad) ^ (l15 & 7)) * 8;   // swizzled read slot
#pragma unroll
      for (int i = 0; i < 4; i++) {
        af[i] = *(const bf16x8*)(As + (wm + i * 16 + l15) * BK + sa);
        bfv[i] = *(const bf16x8*)(Bs + (wn + i * 16 + l15) * BK + sa);
      }
#pragma unroll
      for (int mt = 0; mt < 4; mt++)
#pragma unroll
        for (int nt = 0; nt < 4; nt++)
          acc[mt][nt] = __builtin_amdgcn_mfma_f32_16x16x32_bf16(
              af[mt], bfv[nt], acc[mt][nt], 0, 0, 0);
    }
  }
  // epilogue: C/D layout col=lane&15, row=quad*4+reg (m89/m91-verified)
#pragma unroll
  for (int nt = 0; nt < 4; nt++) {
    int col = n0 + wn + nt * 16 + l15;
    float bv = bias[col];
#pragma unroll
    for (int mt = 0; mt < 4; mt++) {
      int row = m0 + wm + mt * 16 + quad * 4;
#pragma unroll
      for (int r = 0; r < 4; r++) {
        float v = acc[mt][nt][r] + bv;
        size_t idx2 = (size_t)(row + r) * N + col;
        if (EPI == 4) {
          v += res[idx2];
          ((float*)Cv)[idx2] = v;
        } else {
          if (EPI == 2) v = 0.5f * v * (1.0f + erff(v * 0.70710678118654752f));
          ((u16*)Cv)[idx2] = f2bf(v);
        }
      }
    }
  }
}

// ---------------------------------------------------------------- attention
// flash-style; q,k: [16384,768] bf16 head-sliced; vt: [bh][96][1024]; o same
// R1: padded LDS strides (conflicts 3.4e7 -> 1.6e7). R2/R3: 2-phase
// schedule, double-buffered ks/vts, wraparound reg prefetch, ONE barrier/kt.
// R4: XCD swizzle (each XCD owns 16 bh -> K/V L2-resident); per-lane
// partial li (reduce once at end, kills shfl-sum per row per iter);
// scale folded into exp args (raw-domain max tracking).
#define QSS 104
#define VSS 72
#define PSS 72
__global__ __launch_bounds__(256, 2) void attn_k(const u16* __restrict__ q,
                                                 const u16* __restrict__ k,
                                                 const u16* __restrict__ vt,
                                                 u16* __restrict__ o) {
  __shared__ u16 qs[64 * QSS];
  __shared__ u16 ks[2][64 * QSS];
  __shared__ u16 vts[2][96 * VSS];
  __shared__ u16 ps[4 * 16 * PSS];
  int tid = threadIdx.x, lane = tid & 63, w = tid >> 6;
  int l15 = lane & 15, quad = lane >> 4;
  // XCD swizzle: grid (16,128); give each XCD 16 contiguous bh (all qt)
  {
  }
  int f = blockIdx.y * 16 + blockIdx.x;
  int xcd = f & 7, idx = f >> 3;        // idx in [0,256)
  int bh = xcd * 16 + (idx & 15);
  int qt = idx >> 4;
  int b = bh >> 3, h = bh & 7;
  const u16* qbase = q + (size_t)(b * 1024 + qt * 64) * 768 + h * 96;
  const u16* kbase = k + (size_t)(b * 1024) * 768 + h * 96;
  const u16* vtbase = vt + (size_t)bh * 96 * 1024;
  // per-thread staging coordinates (3 chunks each for K and VT)
  int kr[3], ko[3], vr[3], vo[3];
#pragma unroll
  for (int i = 0; i < 3; i++) {
    int c = tid + i * 256;
    kr[i] = c / 12; ko[i] = (c % 12) * 8;
    vr[i] = c >> 3; vo[i] = (c & 7) * 8;
  }
  // Q stage
#pragma unroll
  for (int i = 0; i < 3; i++)
    *(uint4*)(qs + kr[i] * QSS + ko[i]) =
        *(const uint4*)(qbase + (size_t)kr[i] * 768 + ko[i]);
  // prologue: stage tile 0
  uint4 kreg[3], vreg[3];
#pragma unroll
  for (int i = 0; i < 3; i++) {
    kreg[i] = *(const uint4*)(kbase + (size_t)kr[i] * 768 + ko[i]);
    vreg[i] = *(const uint4*)(vtbase + (size_t)vr[i] * 1024 + vo[i]);
  }
#pragma unroll
  for (int i = 0; i < 3; i++) {
    *(uint4*)(ks[0] + kr[i] * QSS + ko[i]) = kreg[i];
    *(uint4*)(vts[0] + vr[i] * VSS + vo[i]) = vreg[i];
  }
  __syncthreads();

  float mi[4], li[4];   // mi: RAW-domain running max; li: per-lane PARTIAL sum
#pragma unroll
  for (int r = 0; r < 4; r++) { mi[r] = -1e30f; li[r] = 0.f; }
  f32x4 oacc[6] = {};
  const float scale = 0.10206207261596577f; // 1/sqrt(96)
  for (int kt = 0; kt < 16; kt++) {
    int cur = kt & 1, nxt = cur ^ 1;
    int ktn = (kt + 1) & 15;  // wraparound: last iter re-fetches tile 0
    // issue prefetch of next tile (completion waited only at the ds_write
    // block after PV — ~2000cy of compute hides the latency)
#pragma unroll
    for (int i = 0; i < 3; i++) {
      kreg[i] = *(const uint4*)(kbase + (size_t)(ktn * 64 + kr[i]) * 768 + ko[i]);
      vreg[i] = *(const uint4*)(vtbase + (size_t)vr[i] * 1024 + ktn * 64 + vo[i]);
    }
    // QK^T on current buffer
    f32x4 s[4] = {};
#pragma unroll
    for (int kk = 0; kk < 3; kk++) {
      bf16x8 a = *(const bf16x8*)(qs + (w * 16 + l15) * QSS + kk * 32 + quad * 8);
#pragma unroll
      for (int nt = 0; nt < 4; nt++) {
        bf16x8 bb =
            *(const bf16x8*)(ks[cur] + (nt * 16 + l15) * QSS + kk * 32 + quad * 8);
        s[nt] = __builtin_amdgcn_mfma_f32_16x16x32_bf16(a, bb, s[nt], 0, 0, 0);
      }
    }
    // online softmax (4 rows per lane-group via quad); raw-domain max
#pragma unroll
    for (int r = 0; r < 4; r++) {
      float sv[4], mx = -1e30f;
#pragma unroll
      for (int nt = 0; nt < 4; nt++) {
        sv[nt] = s[nt][r];
        mx = fmaxf(mx, sv[nt]);
      }
#pragma unroll
      for (int off = 1; off < 16; off <<= 1) mx = fmaxf(mx, __shfl_xor(mx, off, 16));
      float mnew = fmaxf(mi[r], mx);
      float alpha = __expf((mi[r] - mnew) * scale);
      float rs = 0.f;
#pragma unroll
      for (int nt = 0; nt < 4; nt++) {
        sv[nt] = __expf((sv[nt] - mnew) * scale);
        rs += sv[nt];
      }
      li[r] = li[r] * alpha + rs;   // per-lane partial; reduced after loop
      mi[r] = mnew;
#pragma unroll
      for (int ht = 0; ht < 6; ht++) oacc[ht][r] *= alpha;
      int prow = quad * 4 + r;
#pragma unroll
      for (int nt = 0; nt < 4; nt++)
        ps[w * 16 * PSS + prow * PSS + nt * 16 + l15] = f2bf(sv[nt]);
    }
    // ps is wave-private: order write->read within the wave, no barrier
    asm volatile("s_waitcnt lgkmcnt(0)" ::: "memory");
    // PV on current buffer
#pragma unroll
    for (int kk = 0; kk < 2; kk++) {
      bf16x8 a = *(const bf16x8*)(ps + w * 16 * PSS + l15 * PSS + kk * 32 + quad * 8);
#pragma unroll
      for (int ht = 0; ht < 6; ht++) {
        bf16x8 bb =
            *(const bf16x8*)(vts[cur] + (ht * 16 + l15) * VSS + kk * 32 + quad * 8);
        oacc[ht] = __builtin_amdgcn_mfma_f32_16x16x32_bf16(a, bb, oacc[ht], 0, 0, 0);
      }
    }
    // write prefetched tile into next buffer (freed by the barrier that
    // ended iteration kt-1), then the single per-iteration barrier
#pragma unroll
    for (int i = 0; i < 3; i++) {
      *(uint4*)(ks[nxt] + kr[i] * QSS + ko[i]) = kreg[i];
      *(uint4*)(vts[nxt] + vr[i] * VSS + vo[i]) = vreg[i];
    }
    __syncthreads();
  }
  // reduce per-lane partial li across the 16-lane row group (once)
#pragma unroll
  for (int r = 0; r < 4; r++)
#pragma unroll
    for (int off = 1; off < 16; off <<= 1) li[r] += __shfl_xor(li[r], off, 16);
  u16* obase = o + (size_t)(b * 1024 + qt * 64 + w * 16) * 768 + h * 96;
#pragma unroll
  for (int r = 0; r < 4; r++) {
    float inv = 1.0f / li[r];
    int row = quad * 4 + r;
#pragma unroll
    for (int ht = 0; ht < 6; ht++)
      obase[(size_t)row * 768 + ht * 16 + l15] = f2bf(oacc[ht][r] * inv);
  }
}

// ---------------------------------------------------------------- launch
// d_out is FP32 (reference output dtype). y1 lives in d_out as fp32;
// final GEMM reads res=y1 and writes out 1:1-aliased (safe: each (row,col)
// is read-then-written by exactly one thread).
// ws: weights 14.2MB + 4 x 25.2MB bf16 buffers = 115MB (R2-proven safe).
extern "C" void kernel_launch(void* const* d_in, const int* in_sizes, int n_in,
                              void* d_out, int out_size, void* d_ws,
                              size_t ws_size, hipStream_t stream) {
  const float* x = (const float*)d_in[0];
  const float* gamma = (const float*)d_in[1];
  const float* beta = (const float*)d_in[2];
  const float* Wq = (const float*)d_in[3];
  const float* bq = (const float*)d_in[4];
  const float* Wk = (const float*)d_in[5];
  const float* bk = (const float*)d_in[6];
  const float* Wv = (const float*)d_in[7];
  const float* bv = (const float*)d_in[8];
  const float* Wo = (const float*)d_in[9];
  const float* bo = (const float*)d_in[10];
  const float* W1 = (const float*)d_in[11];
  const float* b1 = (const float*)d_in[12];
  const float* W2 = (const float*)d_in[13];
  const float* b2 = (const float*)d_in[14];
  float* out = (float*)d_out;

  char* ws = (char*)d_ws;
  size_t off = 0;
  auto alloc = [&](size_t elems) {
    u16* p = (u16*)(ws + off);
    off += elems * sizeof(u16);
    return p;
  };
  u16* WqT = alloc(768 * 768);
  u16* WkT = alloc(768 * 768);
  u16* WvT = alloc(768 * 768);
  u16* WoT = alloc(768 * 768);
  u16* W1T = alloc((size_t)768 * 3072);    // [3072,768]
  u16* W2T = alloc((size_t)3072 * 768);    // [768,3072]
  u16* hb = alloc((size_t)16384 * 768);    // h -> VT
  u16* qb = alloc((size_t)16384 * 768);    // q
  u16* kb = alloc((size_t)16384 * 768);    // k -> h2
  u16* vb = alloc((size_t)16384 * 768);    // v -> attn_out -> f-chunk

  // weight transposes fp32 -> bf16 [N,K]
  transpose_k<<<dim3(24, 24), 256, 0, stream>>>(Wq, WqT, 768, 768);
  transpose_k<<<dim3(24, 24), 256, 0, stream>>>(Wk, WkT, 768, 768);
  transpose_k<<<dim3(24, 24), 256, 0, stream>>>(Wv, WvT, 768, 768);
  transpose_k<<<dim3(24, 24), 256, 0, stream>>>(Wo, WoT, 768, 768);
  transpose_k<<<dim3(96, 24), 256, 0, stream>>>(W1, W1T, 768, 3072);
  transpose_k<<<dim3(24, 96), 256, 0, stream>>>(W2, W2T, 3072, 768);

  // LN1: x(fp32) -> h(bf16)
  ln_f32_k<<<16384, 256, 0, stream>>>(x, gamma, beta, hb);
  // QKV projections (bf16)
  gemm_bt<0><<<dim3(128, 6), 256, 0, stream>>>(hb, WqT, bq, nullptr, qb,
                                               16384, 768, 768);
  gemm_bt<0><<<dim3(128, 6), 256, 0, stream>>>(hb, WkT, bk, nullptr, kb,
                                               16384, 768, 768);
  gemm_bt<0><<<dim3(128, 6), 256, 0, stream>>>(hb, WvT, bv, nullptr, vb,
                                               16384, 768, 768);
  // V -> VT [bh][96][1024] into hb (h dead)
  vtrans_k<<<dim3(3, 32, 128), 256, 0, stream>>>(vb, hb);
  // attention -> vb (v dead after vtrans)
  attn_k<<<dim3(16, 128), 256, 0, stream>>>(qb, kb, hb, vb);
  // y1(fp32, in d_out) = attn @ Wo + bo + x
  gemm_bt<4><<<dim3(128, 6), 256, 0, stream>>>(vb, WoT, bo, x, out,
                                               16384, 768, 768);
  // h2 = LN(y1) -> kb (k dead)
  ln_f32_k<<<16384, 256, 0, stream>>>(out, gamma, beta, kb);
  // FFN in 4 M-chunks of 4096 rows; f-chunk [4096,3072] bf16 fits vb
  for (int c = 0; c < 4; c++) {
    const u16* h2c = kb + (size_t)c * 4096 * 768;
    const float* y1c = out + (size_t)c * 4096 * 768;
    float* outc = out + (size_t)c * 4096 * 768;
    gemm_bt<2><<<dim3(32, 24), 256, 0, stream>>>(h2c, W1T, b1, nullptr, vb,
                                                 4096, 3072, 768);
    gemm_bt<4><<<dim3(32, 6), 256, 0, stream>>>(vb, W2T, b2, y1c, outc,
                                                4096, 768, 3072);
  }
}